// Round 8
// baseline (257.106 us; speedup 1.0000x reference)
//
#include <hip/hip_runtime.h>

// WaveNet inference on MFMA. Exploits: (1) only last timestep feeds the FC
// head, (2) skip overwritten each layer (only layer 15's matters),
// (3) receptive field at t=T-1 is 77 steps.
// Round 8: TWO batches per block (NT=512, grid=8). Waves 0-3 batch A,
// 4-7 batch B -> each SIMD gets 2 independent instruction streams (latency
// hiding; rounds 2-7 ran 1 wave/SIMD, 86% stall). Weight LDS shared between
// batches (lockstep); residual carry bf16 (fits 64KB static LDS); B-frags
// in lane-sequential order (round-7 layout was 8-way bank conflicted).

#define BB 16
#define TT 8192
#define LL 16
#define W0 77
#define NT 512

typedef __attribute__((ext_vector_type(8)))  short short8;
typedef __attribute__((ext_vector_type(16))) float float16;

#define MFMA_B16(a, b, c) __builtin_amdgcn_mfma_f32_32x32x16_bf16(a, b, c, 0, 0, 0)

__device__ __forceinline__ short f2bs(float f) {   // f32 -> bf16 bits, RNE
  union { float ff; unsigned u; } v; v.ff = f;
  unsigned u = v.u;
  return (short)((u + 0x7FFFu + ((u >> 16) & 1u)) >> 16);
}
__device__ __forceinline__ float b2f(short h) {
  union { unsigned u; float f; } v;
  v.u = ((unsigned)(unsigned short)h) << 16; return v.f;
}
__device__ __forceinline__ float fast_sigmoid(float x) {
  return 1.f / (1.f + __expf(-x));
}
__device__ __forceinline__ float fast_tanh(float x) {
  return 2.f / (1.f + __expf(-2.f * x)) - 1.f;
}

// A-fragment halves: A[m][k], m=lane&31, k-local=(lane>>5)*8+j.
__device__ __forceinline__ void afrag2(const short* src, int row, int kh, short8* out) {
  #pragma unroll
  for (int h = 0; h < 2; h++)
    out[h] = *(const short8*)&src[row * 32 + 16 * h + 8 * kh];
}
// B-fragment halves, lane-sequential LDS order: lane l reads chunk l (16B).
__device__ __forceinline__ void bfragL(const short* bw, int mat, int lane, short8* out) {
  #pragma unroll
  for (int h = 0; h < 2; h++)
    out[h] = *(const short8*)&bw[((mat * 2 + h) * 64 + lane) * 8];
}

__global__ __launch_bounds__(NT, 2) void wavenet_kernel(
    const int* __restrict__ tokens,
    const float* __restrict__ emb,
    const float* __restrict__ init_w, const float* __restrict__ init_b,
    const float* __restrict__ dil_w,  const float* __restrict__ dil_b,
    const float* __restrict__ filt_w, const float* __restrict__ filt_b,
    const float* __restrict__ gate_w, const float* __restrict__ gate_b,
    const float* __restrict__ res_w,  const float* __restrict__ res_b,
    const float* __restrict__ skip_w, const float* __restrict__ skip_b,
    const float* __restrict__ end1_w, const float* __restrict__ end1_b,
    const float* __restrict__ end2_w, const float* __restrict__ end2_b,
    const float* __restrict__ fc1_w,  const float* __restrict__ fc1_b,
    const float* __restrict__ fc2_w,  const float* __restrict__ fc2_b,
    const float* __restrict__ fc3_w,  const float* __restrict__ fc3_b,
    const float* __restrict__ fc4_w,  const float* __restrict__ fc4_b,
    float* __restrict__ out)
{
  // weights: double-buffered bf16 fragments, SHARED between both batches.
  // layout: [buf][(mat*2+h)*64 + lane]*8+j  (lane-sequential b128 reads)
  __shared__ __align__(16) short bfw[2][7168];
  __shared__ float bias2[2][128];
  // per-batch activations (bf16 only; residual carry is bf16 this round)
  __shared__ __align__(16) short xbuf_bf[2][W0 * 32];
  __shared__ __align__(16) short resbuf_bf[2][76 * 32];
  __shared__ __align__(16) short xmid_bf[2][76 * 32];
  __shared__ int tok[2][W0];

  const int tid  = threadIdx.x;
  const int lane = tid & 63;
  const int bat  = tid >> 8;            // 0: waves 0-3, 1: waves 4-7
  const int twv  = (tid >> 6) & 3;      // tile wave within batch
  const int m    = lane & 31;
  const int kh   = lane >> 5;
  const int tid2 = tid & 255;           // index within batch group
  const int cc   = tid2 & 31;
  const int g2   = tid2 >> 5;           // 0..7
  const int bglob = blockIdx.x * 2 + bat;

  // weight prefetch: thread handles q = 2*qh + qi, qh = tid>>8
  const int qh = bat;
  float pw[7][2];
  float pb[4];

  float* iwT = (float*)&bfw[1][0];      // init conv weights alias buf1

  // ---- stage 0 ----
  if (tid2 < W0) tok[bat][tid2] = tokens[bglob * TT + (TT - 1 - tid2)];
  for (int idx = tid; idx < 100 * 32; idx += NT) {
    int e = idx >> 5, c2 = idx & 31;
    iwT[idx] = init_w[c2 * 100 + e];
  }
  if (tid < 32) bias2[0][96 + tid] = init_b[tid];   // park init bias (buf0 unused yet)

  #pragma unroll
  for (int qi = 0; qi < 2; qi++) {      // prefetch layer 0
    int rc = g2 + 8 * (2 * qh + qi);
    int base = cc * 32 + rc;
    pw[0][qi] = dil_w[base * 2 + 0];
    pw[1][qi] = dil_w[base * 2 + 1];
    pw[2][qi] = filt_w[base * 2 + 0];
    pw[3][qi] = filt_w[base * 2 + 1];
    pw[4][qi] = gate_w[base * 2 + 0];
    pw[5][qi] = gate_w[base * 2 + 1];
    pw[6][qi] = res_w[base];
  }
  if (tid < 32) {
    pb[0] = dil_b[tid]; pb[1] = filt_b[tid];
    pb[2] = gate_b[tid]; pb[3] = res_b[tid];
  }
  __syncthreads();

  // ---- init conv (each 256-group does its batch) ----
  {
    const float bc = bias2[0][96 + cc];
    short* xb = xbuf_bf[bat];
    for (int base0 = 0; base0 < W0; base0 += 32) {
      float acc[4] = {bc, bc, bc, bc};
      const float* er[4];
      #pragma unroll
      for (int j = 0; j < 4; j++) {
        int u = base0 + g2 + 8 * j; if (u > W0 - 1) u = W0 - 1;
        er[j] = emb + tok[bat][u] * 100;
      }
      #pragma unroll 5
      for (int eq = 0; eq < 100; eq += 4) {
        float w0 = iwT[(eq+0)*32+cc], w1 = iwT[(eq+1)*32+cc];
        float w2 = iwT[(eq+2)*32+cc], w3 = iwT[(eq+3)*32+cc];
        #pragma unroll
        for (int j = 0; j < 4; j++) {
          float4 e4 = *(const float4*)(er[j] + eq);
          acc[j] += (w0 * e4.x + w1 * e4.y) + (w2 * e4.z + w3 * e4.w);
        }
      }
      #pragma unroll
      for (int j = 0; j < 4; j++) {
        int u = base0 + g2 + 8 * j;
        if (u < W0) xb[u * 32 + cc] = f2bs(acc[j]);
      }
    }
  }
  // commit layer 0 to buf0 (iwT sat in buf1 — disjoint)
  #pragma unroll
  for (int mat = 0; mat < 7; mat++)
    #pragma unroll
    for (int qi = 0; qi < 2; qi++)
      bfw[0][((mat * 2 + qh) * 64 + qi * 32 + cc) * 8 + g2] = f2bs(pw[mat][qi]);
  if (tid < 32) {
    bias2[0][tid] = pb[0]; bias2[0][32+tid] = pb[1];
    bias2[0][64+tid] = pb[2]; bias2[0][96+tid] = pb[3];
  }
  __syncthreads();

  // ---- 16 layers, 2 barriers each ----
  int Win = W0;
  short* xb = xbuf_bf[bat];
  short* rb = resbuf_bf[bat];
  short* xm = xmid_bf[bat];
  for (int i = 0; i < LL; i++) {
    const int d = 1 << (i & 3);
    const int Wout = Win - d - 1;
    const int T1 = (Wout + 32) >> 5;
    const int T2 = (Wout + 31) >> 5;
    const short* bw = bfw[i & 1];
    const float* bs = bias2[i & 1];

    // prefetch layer i+1 (latency hidden under both phases)
    if (i + 1 < LL) {
      const int ii = i + 1;
      #pragma unroll
      for (int qi = 0; qi < 2; qi++) {
        int rc = g2 + 8 * (2 * qh + qi);
        int base = (ii * 32 + cc) * 32 + rc;
        pw[0][qi] = dil_w[base * 2 + 0];
        pw[1][qi] = dil_w[base * 2 + 1];
        pw[2][qi] = filt_w[base * 2 + 0];
        pw[3][qi] = filt_w[base * 2 + 1];
        pw[4][qi] = gate_w[base * 2 + 0];
        pw[5][qi] = gate_w[base * 2 + 1];
        pw[6][qi] = res_w[base];
      }
      if (tid < 32) {
        pb[0] = dil_b[ii * 32 + tid]; pb[1] = filt_b[ii * 32 + tid];
        pb[2] = gate_b[ii * 32 + tid]; pb[3] = res_b[ii * 32 + tid];
      }
    }

    // ---- phase1: residual[vr] = db + D0@x[vr+d] + D1@x[vr] ----
    if (twv < T1) {
      const int R = twv * 32;
      short8 bD0[2], bD1[2];
      bfragL(bw, 0, lane, bD0);
      bfragL(bw, 1, lane, bD1);
      int vra = R + m + d; if (vra > Win - 1) vra = Win - 1;
      int vrz = R + m;     if (vrz > Win - 1) vrz = Win - 1;
      short8 aA[2], aZ[2];
      afrag2(xb, vra, kh, aA);
      afrag2(xb, vrz, kh, aZ);
      float16 acc;
      const float bc = bs[m];
      #pragma unroll
      for (int r = 0; r < 16; r++) acc[r] = bc;
      acc = MFMA_B16(aA[0], bD0[0], acc);
      acc = MFMA_B16(aA[1], bD0[1], acc);
      acc = MFMA_B16(aZ[0], bD1[0], acc);
      acc = MFMA_B16(aZ[1], bD1[1], acc);
      #pragma unroll
      for (int r = 0; r < 16; r++) {
        int row = (r & 3) + 8 * (r >> 2) + 4 * kh;
        int vr = R + row;
        if (vr <= Wout) rb[vr * 32 + m] = f2bs(acc[r]);
      }
    }
    __syncthreads();

    // ---- phase2+3 (same wave & tile, wave-local handoff) ----
    if (twv < T2) {
      const int R = twv * 32;
      short8 bF0[2], bF1[2], bG0[2], bG1[2];
      bfragL(bw, 2, lane, bF0);
      bfragL(bw, 3, lane, bF1);
      bfragL(bw, 4, lane, bG0);
      bfragL(bw, 5, lane, bG1);
      int r1 = R + m + 1; if (r1 > Wout) r1 = Wout;
      int r0 = R + m;     if (r0 > Wout) r0 = Wout;
      short8 a1[2], a0[2];
      afrag2(rb, r1, kh, a1);
      afrag2(rb, r0, kh, a0);
      float16 accF, accG;
      const float bf = bs[32 + m], bg = bs[64 + m];
      #pragma unroll
      for (int r = 0; r < 16; r++) { accF[r] = bf; accG[r] = bg; }
      accF = MFMA_B16(a1[0], bF0[0], accF);
      accF = MFMA_B16(a1[1], bF0[1], accF);
      accF = MFMA_B16(a0[0], bF1[0], accF);
      accF = MFMA_B16(a0[1], bF1[1], accF);
      accG = MFMA_B16(a1[0], bG0[0], accG);
      accG = MFMA_B16(a1[1], bG0[1], accG);
      accG = MFMA_B16(a0[0], bG1[0], accG);
      accG = MFMA_B16(a0[1], bG1[1], accG);
      #pragma unroll
      for (int r = 0; r < 16; r++) {
        int row = (r & 3) + 8 * (r >> 2) + 4 * kh;
        int uf = R + row;
        if (uf < Wout)
          xm[uf * 32 + m] = f2bs(fast_tanh(accF[r]) * fast_sigmoid(accG[r]));
      }
      asm volatile("s_waitcnt lgkmcnt(0)" ::: "memory");

      // phase3: xnext = rb_bias + R@xmid + residual[uf+1] (bf16 carry)
      short8 bR[2];
      bfragL(bw, 6, lane, bR);
      int rx = R + m; if (rx > Wout - 1) rx = Wout - 1;
      short8 aX[2];
      afrag2(xm, rx, kh, aX);
      float16 accX;
      const float br = bs[96 + m];
      #pragma unroll
      for (int r = 0; r < 16; r++) {
        int row = (r & 3) + 8 * (r >> 2) + 4 * kh;
        int rr = R + row + 1; if (rr > Wout) rr = Wout;
        accX[r] = br + b2f(rb[rr * 32 + m]);
      }
      accX = MFMA_B16(aX[0], bR[0], accX);
      accX = MFMA_B16(aX[1], bR[1], accX);
      #pragma unroll
      for (int r = 0; r < 16; r++) {
        int row = (r & 3) + 8 * (r >> 2) + 4 * kh;
        int uf = R + row;
        if (uf < Wout) xb[uf * 32 + m] = f2bs(accX[r]);
      }
    }

    // commit layer i+1 into other buffer (no extra barrier)
    if (i + 1 < LL) {
      short* bwN = bfw[(i + 1) & 1];
      #pragma unroll
      for (int mat = 0; mat < 7; mat++)
        #pragma unroll
        for (int qi = 0; qi < 2; qi++)
          bwN[((mat * 2 + qh) * 64 + qi * 32 + cc) * 8 + g2] = f2bs(pw[mat][qi]);
      if (tid < 32) {
        float* bN = bias2[(i + 1) & 1];
        bN[tid] = pb[0]; bN[32+tid] = pb[1]; bN[64+tid] = pb[2]; bN[96+tid] = pb[3];
      }
    }
    __syncthreads();
    Win = Wout;
  }

  // ---- tail (f32 VALU, per 256-group): skip(l15) -> end1 -> end2 -> fc ----
  float* vecA = (float*)&xbuf_bf[bat][0];     // xbuf dead; 2KB alias
  float* vecB = vecA + 256;
  {
    float acc = skip_b[15 * 256 + tid2];
    const float* wr = skip_w + (15 * 256 + tid2) * 32;
    float s = 0.f;
    #pragma unroll
    for (int k = 0; k < 32; k += 4) {
      float4 w = *(const float4*)&wr[k];
      s += (w.x * b2f(xm[k]) + w.y * b2f(xm[k+1])) + (w.z * b2f(xm[k+2]) + w.w * b2f(xm[k+3]));
    }
    __syncthreads();                           // xbuf fully dead before alias write
    vecA[tid2] = fmaxf(acc + s, 0.f);
  }
  __syncthreads();
  {
    const float* wr = end1_w + tid2 * 256;
    float a4[4] = {0.f, 0.f, 0.f, 0.f};
    #pragma unroll 4
    for (int k = 0; k < 256; k += 16) {
      #pragma unroll
      for (int q = 0; q < 4; q++) {
        float4 w = *(const float4*)&wr[k + 4 * q];
        a4[q] += (w.x * vecA[k+4*q] + w.y * vecA[k+4*q+1]) + (w.z * vecA[k+4*q+2] + w.w * vecA[k+4*q+3]);
      }
    }
    vecB[tid2] = fmaxf(end1_b[tid2] + (a4[0] + a4[1]) + (a4[2] + a4[3]), 0.f);
  }
  __syncthreads();
  float h2;
  {
    const float* wr = end2_w + tid2 * 256;
    float a4[4] = {0.f, 0.f, 0.f, 0.f};
    #pragma unroll 4
    for (int k = 0; k < 256; k += 16) {
      #pragma unroll
      for (int q = 0; q < 4; q++) {
        float4 w = *(const float4*)&wr[k + 4 * q];
        a4[q] += (w.x * vecB[k+4*q] + w.y * vecB[k+4*q+1]) + (w.z * vecB[k+4*q+2] + w.w * vecB[k+4*q+3]);
      }
    }
    h2 = end2_b[tid2] + (a4[0] + a4[1]) + (a4[2] + a4[3]);
  }
  __syncthreads();
  vecA[tid2] = h2;
  __syncthreads();
  if (tid2 < 128) {
    const float* wr = fc1_w + tid2 * 256;
    float a4[4] = {0.f, 0.f, 0.f, 0.f};
    #pragma unroll 4
    for (int k = 0; k < 256; k += 16) {
      #pragma unroll
      for (int q = 0; q < 4; q++) {
        float4 w = *(const float4*)&wr[k + 4 * q];
        a4[q] += (w.x * vecA[k+4*q] + w.y * vecA[k+4*q+1]) + (w.z * vecA[k+4*q+2] + w.w * vecA[k+4*q+3]);
      }
    }
    vecB[tid2] = fmaxf(fc1_b[tid2] + (a4[0] + a4[1]) + (a4[2] + a4[3]), 0.f);
  }
  __syncthreads();
  if (tid2 < 128) {
    const float* wr = fc2_w + tid2 * 128;
    float a4[4] = {0.f, 0.f, 0.f, 0.f};
    #pragma unroll 2
    for (int k = 0; k < 128; k += 16) {
      #pragma unroll
      for (int q = 0; q < 4; q++) {
        float4 w = *(const float4*)&wr[k + 4 * q];
        a4[q] += (w.x * vecB[k+4*q] + w.y * vecB[k+4*q+1]) + (w.z * vecB[k+4*q+2] + w.w * vecB[k+4*q+3]);
      }
    }
    vecA[tid2] = fmaxf(fc2_b[tid2] + (a4[0] + a4[1]) + (a4[2] + a4[3]), 0.f);
  }
  __syncthreads();
  if (tid2 < 64) {
    const float* wr = fc3_w + tid2 * 128;
    float a4[4] = {0.f, 0.f, 0.f, 0.f};
    #pragma unroll 2
    for (int k = 0; k < 128; k += 16) {
      #pragma unroll
      for (int q = 0; q < 4; q++) {
        float4 w = *(const float4*)&wr[k + 4 * q];
        a4[q] += (w.x * vecA[k+4*q] + w.y * vecA[k+4*q+1]) + (w.z * vecA[k+4*q+2] + w.w * vecA[k+4*q+3]);
      }
    }
    vecB[tid2] = fmaxf(fc3_b[tid2] + (a4[0] + a4[1]) + (a4[2] + a4[3]), 0.f);
  }
  __syncthreads();
  {
    const float* wr = fc4_w + tid2 * 64;
    float a4[4] = {0.f, 0.f, 0.f, 0.f};
    #pragma unroll
    for (int k = 0; k < 64; k += 16) {
      #pragma unroll
      for (int q = 0; q < 4; q++) {
        float4 w = *(const float4*)&wr[k + 4 * q];
        a4[q] += (w.x * vecB[k+4*q] + w.y * vecB[k+4*q+1]) + (w.z * vecB[k+4*q+2] + w.w * vecB[k+4*q+3]);
      }
    }
    out[bglob * 256 + tid2] = fc4_b[tid2] + (a4[0] + a4[1]) + (a4[2] + a4[3]);
  }
}

extern "C" void kernel_launch(void* const* d_in, const int* in_sizes, int n_in,
                              void* d_out, int out_size, void* d_ws, size_t ws_size,
                              hipStream_t stream) {
  wavenet_kernel<<<BB / 2, NT, 0, stream>>>(
      (const int*)d_in[0],    (const float*)d_in[1],  (const float*)d_in[2],  (const float*)d_in[3],
      (const float*)d_in[4],  (const float*)d_in[5],  (const float*)d_in[6],  (const float*)d_in[7],
      (const float*)d_in[8],  (const float*)d_in[9],  (const float*)d_in[10], (const float*)d_in[11],
      (const float*)d_in[12], (const float*)d_in[13], (const float*)d_in[14], (const float*)d_in[15],
      (const float*)d_in[16], (const float*)d_in[17], (const float*)d_in[18], (const float*)d_in[19],
      (const float*)d_in[20], (const float*)d_in[21], (const float*)d_in[22], (const float*)d_in[23],
      (const float*)d_in[24], (const float*)d_in[25], (float*)d_out);
}

// Round 9
// 228.864 us; speedup vs baseline: 1.1234x; 1.1234x over previous
//
#include <hip/hip_runtime.h>

// WaveNet inference on MFMA. Exploits: (1) only last timestep feeds the FC
// head, (2) skip overwritten each layer (only layer 15's matters),
// (3) receptive field at t=T-1 is 77 steps.
// Round 9: grid=16 (one CU per batch — round 8 proved halving CUs loses).
// Wave 0 runs the whole serial layer chain BARRIER-FREE (in-wave lgkmcnt
// ordering); waves 1-3 stage next layer's bf16 weight fragments from global
// into a double-buffered LDS region (1 barrier/layer, stagers arrive early).
// Init conv is MFMA over LDS-staged bf16 emb rows (K=112 zero-padded).

#define BB 16
#define TT 8192
#define LL 16
#define W0 77
#define NT 256

typedef __attribute__((ext_vector_type(8)))  short short8;
typedef __attribute__((ext_vector_type(16))) float float16;

#define MFMA_B16(a, b, c) __builtin_amdgcn_mfma_f32_32x32x16_bf16(a, b, c, 0, 0, 0)

__device__ __forceinline__ short f2bs(float f) {   // f32 -> bf16 bits, RNE
  union { float ff; unsigned u; } v; v.ff = f;
  unsigned u = v.u;
  return (short)((u + 0x7FFFu + ((u >> 16) & 1u)) >> 16);
}
__device__ __forceinline__ float b2f(short h) {
  union { unsigned u; float f; } v;
  v.u = ((unsigned)(unsigned short)h) << 16; return v.f;
}
__device__ __forceinline__ float fast_sigmoid(float x) {
  return 1.f / (1.f + __expf(-x));
}
__device__ __forceinline__ float fast_tanh(float x) {
  return 2.f / (1.f + __expf(-2.f * x)) - 1.f;
}

// A-fragment halves from [row][32] bf16 LDS: A[m][k], k-local=(lane>>5)*8+j.
__device__ __forceinline__ void afrag2(const short* src, int row, int kh, short8* out) {
  out[0] = *(const short8*)&src[row * 32 + 8 * kh];
  out[1] = *(const short8*)&src[row * 32 + 16 + 8 * kh];
}

// Stage layer li's weights as bf16 B-fragments (lane-sequential chunks).
// 896 chunks: chunk = (mat, h, lane'); value j = W[16h+8kh'+j][n].
__device__ __forceinline__ void stage_weights(
    int li, short* dst,
    const float* dil_w, const float* filt_w, const float* gate_w, const float* res_w,
    int t0, int nthr)
{
  for (int cid = t0; cid < 896; cid += nthr) {
    int mat = cid >> 7;
    int rem = cid & 127;
    int h = rem >> 6, ln = rem & 63;
    int n = ln & 31, k2 = ln >> 5;
    int base = (li * 32 + n) * 32 + 16 * h + 8 * k2;
    short8 v;
    if (mat == 6) {
      const float* p = res_w + base;
      #pragma unroll
      for (int j = 0; j < 8; j++) v[j] = f2bs(p[j]);
    } else {
      const float* w = (mat < 2) ? dil_w : (mat < 4) ? filt_w : gate_w;
      const float* p = w + base * 2 + (mat & 1);
      #pragma unroll
      for (int j = 0; j < 8; j++) v[j] = f2bs(p[2 * j]);
    }
    *(short8*)&dst[((mat * 2 + h) * 64 + ln) * 8] = v;
  }
}

__global__ __launch_bounds__(NT, 1) void wavenet_kernel(
    const int* __restrict__ tokens,
    const float* __restrict__ emb,
    const float* __restrict__ init_w, const float* __restrict__ init_b,
    const float* __restrict__ dil_w,  const float* __restrict__ dil_b,
    const float* __restrict__ filt_w, const float* __restrict__ filt_b,
    const float* __restrict__ gate_w, const float* __restrict__ gate_b,
    const float* __restrict__ res_w,  const float* __restrict__ res_b,
    const float* __restrict__ skip_w, const float* __restrict__ skip_b,
    const float* __restrict__ end1_w, const float* __restrict__ end1_b,
    const float* __restrict__ end2_w, const float* __restrict__ end2_b,
    const float* __restrict__ fc1_w,  const float* __restrict__ fc1_b,
    const float* __restrict__ fc2_w,  const float* __restrict__ fc2_b,
    const float* __restrict__ fc3_w,  const float* __restrict__ fc3_b,
    const float* __restrict__ fc4_w,  const float* __restrict__ fc4_b,
    float* __restrict__ out)
{
  __shared__ __align__(16) short bfw[2][7168];   // weight frags, double buffer
  __shared__ float bias2[2][128];
  __shared__ __align__(16) short xbuf[W0 * 32];
  __shared__ __align__(16) short pool[8624];     // emb stage (init) / rb+xm (layers)
  __shared__ int tok[W0];
  __shared__ float vecA[256], vecB[256];

  short* rb = pool;          // 76*32 = 2432 shorts
  short* xm = pool + 2432;   // 2432 shorts

  const int tid  = threadIdx.x;
  const int lane = tid & 63;
  const int wv   = tid >> 6;
  const int m    = lane & 31;
  const int kh   = lane >> 5;
  const int b    = blockIdx.x;

  // ---- tokens ----
  if (tid < W0) tok[tid] = tokens[b * TT + (TT - 1 - tid)];
  __syncthreads();

  // ---- stage emb rows (bf16, rows padded to 112) ----
  for (int cid = tid; cid < 77 * 14; cid += NT) {
    int u = cid / 14, s = cid % 14;
    const float* er = emb + tok[u] * 100 + s * 8;
    short8 v;
    if (s < 12) {
      #pragma unroll
      for (int j = 0; j < 8; j++) v[j] = f2bs(er[j]);
    } else if (s == 12) {
      #pragma unroll
      for (int j = 0; j < 4; j++) v[j] = f2bs(er[j]);
      #pragma unroll
      for (int j = 4; j < 8; j++) v[j] = 0;
    } else {
      #pragma unroll
      for (int j = 0; j < 8; j++) v[j] = 0;
    }
    *(short8*)&pool[u * 112 + s * 8] = v;
  }
  // stage layer-0 weights + biases (all threads; init conv waits at barrier)
  stage_weights(0, bfw[0], dil_w, filt_w, gate_w, res_w, tid, NT);
  if (tid < 128) {
    const float* bsrc = (tid < 32) ? dil_b : (tid < 64) ? filt_b : (tid < 96) ? gate_b : res_b;
    bias2[0][tid] = bsrc[tid & 31];
  }
  __syncthreads();

  // ---- init conv (wave 0, MFMA over K=112) ----
  if (wv == 0) {
    short8 bi[7];
    #pragma unroll
    for (int s = 0; s < 7; s++) {
      const float* p = init_w + m * 100 + s * 16 + kh * 8;
      short8 v;
      if (s < 6) {
        #pragma unroll
        for (int j = 0; j < 8; j++) v[j] = f2bs(p[j]);
      } else if (kh == 0) {
        #pragma unroll
        for (int j = 0; j < 4; j++) v[j] = f2bs(p[j]);
        #pragma unroll
        for (int j = 4; j < 8; j++) v[j] = 0;
      } else {
        #pragma unroll
        for (int j = 0; j < 8; j++) v[j] = 0;
      }
      bi[s] = v;
    }
    const float binit = init_b[m];
    int u = 0;
    #pragma unroll
    for (int t = 0; t < 3; t++) {
      int R = t * 32;
      u = R + m; if (u > 76) u = 76;
      float16 acc;
      #pragma unroll
      for (int r = 0; r < 16; r++) acc[r] = binit;
      #pragma unroll
      for (int s = 0; s < 7; s++) {
        short8 a = *(const short8*)&pool[u * 112 + s * 16 + kh * 8];
        acc = MFMA_B16(a, bi[s], acc);
      }
      #pragma unroll
      for (int r = 0; r < 16; r++) {
        int row = (r & 3) + 8 * (r >> 2) + 4 * kh;
        int uu = R + row;
        if (uu < W0) xbuf[uu * 32 + m] = f2bs(acc[r]);
      }
    }
  }

  // ---- 16 layers: wave 0 computes (barrier-free), waves 1-3 stage i+1 ----
  int Win = W0;
  for (int i = 0; i < LL; i++) {
    __syncthreads();   // staging of layer i complete; buffers flip
    const int d = 1 << (i & 3);
    const int Wout = Win - d - 1;
    if (wv == 0) {
      const short* bw = bfw[i & 1];
      const float* bs = bias2[i & 1];
      short8 BW[7][2];
      #pragma unroll
      for (int mat = 0; mat < 7; mat++)
        #pragma unroll
        for (int h = 0; h < 2; h++)
          BW[mat][h] = *(const short8*)&bw[((mat * 2 + h) * 64 + lane) * 8];
      const int T1 = (Wout + 32) >> 5;
      const int T2 = (Wout + 31) >> 5;

      // phase1: residual[vr] = db + D0@x[vr+d] + D1@x[vr]
      for (int t = 0; t < T1; t++) {
        int R = t * 32;
        int vra = R + m + d; if (vra > Win - 1) vra = Win - 1;
        int vrz = R + m;     if (vrz > Win - 1) vrz = Win - 1;
        short8 aA[2], aZ[2];
        afrag2(xbuf, vra, kh, aA);
        afrag2(xbuf, vrz, kh, aZ);
        float16 acc;
        const float bc = bs[m];
        #pragma unroll
        for (int r = 0; r < 16; r++) acc[r] = bc;
        acc = MFMA_B16(aA[0], BW[0][0], acc);
        acc = MFMA_B16(aA[1], BW[0][1], acc);
        acc = MFMA_B16(aZ[0], BW[1][0], acc);
        acc = MFMA_B16(aZ[1], BW[1][1], acc);
        #pragma unroll
        for (int r = 0; r < 16; r++) {
          int row = (r & 3) + 8 * (r >> 2) + 4 * kh;
          int vr = R + row;
          if (vr <= Wout) rb[vr * 32 + m] = f2bs(acc[r]);
        }
      }
      asm volatile("s_waitcnt lgkmcnt(0)" ::: "memory");

      // phase2: f/g
      for (int t = 0; t < T2; t++) {
        int R = t * 32;
        int r1 = R + m + 1; if (r1 > Wout) r1 = Wout;
        int r0 = R + m;     if (r0 > Wout) r0 = Wout;
        short8 a1[2], a0[2];
        afrag2(rb, r1, kh, a1);
        afrag2(rb, r0, kh, a0);
        float16 accF, accG;
        const float bf = bs[32 + m], bg = bs[64 + m];
        #pragma unroll
        for (int r = 0; r < 16; r++) { accF[r] = bf; accG[r] = bg; }
        accF = MFMA_B16(a1[0], BW[2][0], accF);
        accF = MFMA_B16(a1[1], BW[2][1], accF);
        accF = MFMA_B16(a0[0], BW[3][0], accF);
        accF = MFMA_B16(a0[1], BW[3][1], accF);
        accG = MFMA_B16(a1[0], BW[4][0], accG);
        accG = MFMA_B16(a1[1], BW[4][1], accG);
        accG = MFMA_B16(a0[0], BW[5][0], accG);
        accG = MFMA_B16(a0[1], BW[5][1], accG);
        #pragma unroll
        for (int r = 0; r < 16; r++) {
          int row = (r & 3) + 8 * (r >> 2) + 4 * kh;
          int uf = R + row;
          if (uf < Wout)
            xm[uf * 32 + m] = f2bs(fast_tanh(accF[r]) * fast_sigmoid(accG[r]));
        }
      }
      asm volatile("s_waitcnt lgkmcnt(0)" ::: "memory");

      // phase3: xnext = rbias + R@xmid + residual[row+1]
      for (int t = 0; t < T2; t++) {
        int R = t * 32;
        int rx = R + m; if (rx > Wout - 1) rx = Wout - 1;
        short8 aX[2];
        afrag2(xm, rx, kh, aX);
        float16 accX;
        const float br = bs[96 + m];
        #pragma unroll
        for (int r = 0; r < 16; r++) {
          int row = (r & 3) + 8 * (r >> 2) + 4 * kh;
          int rr = R + row + 1; if (rr > Wout) rr = Wout;
          accX[r] = br + b2f(rb[rr * 32 + m]);
        }
        accX = MFMA_B16(aX[0], BW[6][0], accX);
        accX = MFMA_B16(aX[1], BW[6][1], accX);
        #pragma unroll
        for (int r = 0; r < 16; r++) {
          int row = (r & 3) + 8 * (r >> 2) + 4 * kh;
          int uf = R + row;
          if (uf < Wout) xbuf[uf * 32 + m] = f2bs(accX[r]);
        }
      }
      asm volatile("s_waitcnt lgkmcnt(0)" ::: "memory");
    } else if (i + 1 < LL) {
      // stagers: layer i+1 fragments into the other buffer
      stage_weights(i + 1, bfw[(i + 1) & 1], dil_w, filt_w, gate_w, res_w,
                    tid - 64, 192);
      int idx = tid - 64;
      if (idx < 128) {
        const float* bsrc = (idx < 32) ? dil_b : (idx < 64) ? filt_b : (idx < 96) ? gate_b : res_b;
        bias2[(i + 1) & 1][idx] = bsrc[(i + 1) * 32 + (idx & 31)];
      }
    }
    Win = Wout;
  }
  __syncthreads();

  // ---- tail (f32 VALU, 4 waves): skip(l15) -> end1 -> end2 -> fc1..fc4 ----
  {
    float acc = skip_b[15 * 256 + tid];
    const float* wr = skip_w + (15 * 256 + tid) * 32;
    #pragma unroll
    for (int k = 0; k < 32; k += 4) {
      float4 w = *(const float4*)&wr[k];
      acc += (w.x * b2f(xm[k]) + w.y * b2f(xm[k+1])) + (w.z * b2f(xm[k+2]) + w.w * b2f(xm[k+3]));
    }
    vecA[tid] = fmaxf(acc, 0.f);
  }
  __syncthreads();
  {
    const float* wr = end1_w + tid * 256;
    float a4[4] = {0.f, 0.f, 0.f, 0.f};
    #pragma unroll 4
    for (int k = 0; k < 256; k += 16) {
      #pragma unroll
      for (int q = 0; q < 4; q++) {
        float4 w = *(const float4*)&wr[k + 4 * q];
        a4[q] += (w.x * vecA[k+4*q] + w.y * vecA[k+4*q+1]) + (w.z * vecA[k+4*q+2] + w.w * vecA[k+4*q+3]);
      }
    }
    vecB[tid] = fmaxf(end1_b[tid] + (a4[0] + a4[1]) + (a4[2] + a4[3]), 0.f);
  }
  __syncthreads();
  float h2;
  {
    const float* wr = end2_w + tid * 256;
    float a4[4] = {0.f, 0.f, 0.f, 0.f};
    #pragma unroll 4
    for (int k = 0; k < 256; k += 16) {
      #pragma unroll
      for (int q = 0; q < 4; q++) {
        float4 w = *(const float4*)&wr[k + 4 * q];
        a4[q] += (w.x * vecB[k+4*q] + w.y * vecB[k+4*q+1]) + (w.z * vecB[k+4*q+2] + w.w * vecB[k+4*q+3]);
      }
    }
    h2 = end2_b[tid] + (a4[0] + a4[1]) + (a4[2] + a4[3]);
  }
  __syncthreads();
  vecA[tid] = h2;
  __syncthreads();
  if (tid < 128) {
    const float* wr = fc1_w + tid * 256;
    float a4[4] = {0.f, 0.f, 0.f, 0.f};
    #pragma unroll 4
    for (int k = 0; k < 256; k += 16) {
      #pragma unroll
      for (int q = 0; q < 4; q++) {
        float4 w = *(const float4*)&wr[k + 4 * q];
        a4[q] += (w.x * vecA[k+4*q] + w.y * vecA[k+4*q+1]) + (w.z * vecA[k+4*q+2] + w.w * vecA[k+4*q+3]);
      }
    }
    vecB[tid] = fmaxf(fc1_b[tid] + (a4[0] + a4[1]) + (a4[2] + a4[3]), 0.f);
  }
  __syncthreads();
  if (tid < 128) {
    const float* wr = fc2_w + tid * 128;
    float a4[4] = {0.f, 0.f, 0.f, 0.f};
    #pragma unroll 2
    for (int k = 0; k < 128; k += 16) {
      #pragma unroll
      for (int q = 0; q < 4; q++) {
        float4 w = *(const float4*)&wr[k + 4 * q];
        a4[q] += (w.x * vecB[k+4*q] + w.y * vecB[k+4*q+1]) + (w.z * vecB[k+4*q+2] + w.w * vecB[k+4*q+3]);
      }
    }
    vecA[tid] = fmaxf(fc2_b[tid] + (a4[0] + a4[1]) + (a4[2] + a4[3]), 0.f);
  }
  __syncthreads();
  if (tid < 64) {
    const float* wr = fc3_w + tid * 128;
    float a4[4] = {0.f, 0.f, 0.f, 0.f};
    #pragma unroll 2
    for (int k = 0; k < 128; k += 16) {
      #pragma unroll
      for (int q = 0; q < 4; q++) {
        float4 w = *(const float4*)&wr[k + 4 * q];
        a4[q] += (w.x * vecA[k+4*q] + w.y * vecA[k+4*q+1]) + (w.z * vecA[k+4*q+2] + w.w * vecA[k+4*q+3]);
      }
    }
    vecB[tid] = fmaxf(fc3_b[tid] + (a4[0] + a4[1]) + (a4[2] + a4[3]), 0.f);
  }
  __syncthreads();
  {
    const float* wr = fc4_w + tid * 64;
    float a4[4] = {0.f, 0.f, 0.f, 0.f};
    #pragma unroll
    for (int k = 0; k < 64; k += 16) {
      #pragma unroll
      for (int q = 0; q < 4; q++) {
        float4 w = *(const float4*)&wr[k + 4 * q];
        a4[q] += (w.x * vecB[k+4*q] + w.y * vecB[k+4*q+1]) + (w.z * vecB[k+4*q+2] + w.w * vecB[k+4*q+3]);
      }
    }
    out[b * 256 + tid] = fc4_b[tid] + (a4[0] + a4[1]) + (a4[2] + a4[3]);
  }
}

extern "C" void kernel_launch(void* const* d_in, const int* in_sizes, int n_in,
                              void* d_out, int out_size, void* d_ws, size_t ws_size,
                              hipStream_t stream) {
  wavenet_kernel<<<BB, NT, 0, stream>>>(
      (const int*)d_in[0],    (const float*)d_in[1],  (const float*)d_in[2],  (const float*)d_in[3],
      (const float*)d_in[4],  (const float*)d_in[5],  (const float*)d_in[6],  (const float*)d_in[7],
      (const float*)d_in[8],  (const float*)d_in[9],  (const float*)d_in[10], (const float*)d_in[11],
      (const float*)d_in[12], (const float*)d_in[13], (const float*)d_in[14], (const float*)d_in[15],
      (const float*)d_in[16], (const float*)d_in[17], (const float*)d_in[18], (const float*)d_in[19],
      (const float*)d_in[20], (const float*)d_in[21], (const float*)d_in[22], (const float*)d_in[23],
      (const float*)d_in[24], (const float*)d_in[25], (float*)d_out);
}

// Round 10
// 212.155 us; speedup vs baseline: 1.2119x; 1.0788x over previous
//
#include <hip/hip_runtime.h>

// WaveNet inference on MFMA. Exploits: (1) only last timestep feeds the FC
// head, (2) skip overwritten each layer (only layer 15's matters),
// (3) receptive field at t=T-1 is 77 steps (window shrinks 77->...->1).
// Round 10 = merge of measured winners:
//  - R7 structure: tiles parallel across waves, 2 barriers/layer (beat R9's
//    single-wave barrier-free chain 117 vs 131 us)
//  - R9 staging: lane-sequential bf16 B-fragment LDS layout (conflict-free
//    b128), chunk-owned prefetch->commit (4x ds_write_b128/thread)
//  - R9 init conv: MFMA over LDS-staged bf16 emb rows (K=112)
//  - bf16 residual carry (absmax 3.9e-3, threshold 14.3e-3)

#define BB 16
#define TT 8192
#define LL 16
#define W0 77
#define NT 256

typedef __attribute__((ext_vector_type(8)))  short short8;
typedef __attribute__((ext_vector_type(16))) float float16;

#define MFMA_B16(a, b, c) __builtin_amdgcn_mfma_f32_32x32x16_bf16(a, b, c, 0, 0, 0)

__device__ __forceinline__ short f2bs(float f) {   // f32 -> bf16 bits, RNE
  union { float ff; unsigned u; } v; v.ff = f;
  unsigned u = v.u;
  return (short)((u + 0x7FFFu + ((u >> 16) & 1u)) >> 16);
}
__device__ __forceinline__ float b2f(short h) {
  union { unsigned u; float f; } v;
  v.u = ((unsigned)(unsigned short)h) << 16; return v.f;
}
__device__ __forceinline__ float fast_sigmoid(float x) {
  return 1.f / (1.f + __expf(-x));
}
__device__ __forceinline__ float fast_tanh(float x) {
  return 2.f / (1.f + __expf(-2.f * x)) - 1.f;
}

// A-fragment halves from [row][32] bf16 LDS: A[m][k], k-local=(lane>>5)*8+j.
__device__ __forceinline__ void afrag2(const short* src, int row, int kh, short8* out) {
  out[0] = *(const short8*)&src[row * 32 + 8 * kh];
  out[1] = *(const short8*)&src[row * 32 + 16 + 8 * kh];
}

// chunk cid in [0,896): mat=cid>>7, h=(cid>>6)&1, ln=cid&63 -> n=ln&31,k2=ln>>5
// value j: W[16h+8k2+j][n] of matrix mat; dst offset = cid*8 shorts (b128).
__device__ __forceinline__ void load_chunk(
    int li, int cid, float* pf,
    const float* dil_w, const float* filt_w, const float* gate_w, const float* res_w)
{
  int mat = cid >> 7;
  int h = (cid >> 6) & 1, ln = cid & 63;
  int n = ln & 31, k2 = ln >> 5;
  int base = (li * 32 + n) * 32 + 16 * h + 8 * k2;
  if (mat == 6) {
    const float* p = res_w + base;
    #pragma unroll
    for (int j = 0; j < 8; j++) pf[j] = p[j];
  } else {
    const float* w = (mat < 2) ? dil_w : (mat < 4) ? filt_w : gate_w;
    const float* p = w + base * 2 + (mat & 1);
    #pragma unroll
    for (int j = 0; j < 8; j++) pf[j] = p[2 * j];
  }
}

__global__ __launch_bounds__(NT, 1) void wavenet_kernel(
    const int* __restrict__ tokens,
    const float* __restrict__ emb,
    const float* __restrict__ init_w, const float* __restrict__ init_b,
    const float* __restrict__ dil_w,  const float* __restrict__ dil_b,
    const float* __restrict__ filt_w, const float* __restrict__ filt_b,
    const float* __restrict__ gate_w, const float* __restrict__ gate_b,
    const float* __restrict__ res_w,  const float* __restrict__ res_b,
    const float* __restrict__ skip_w, const float* __restrict__ skip_b,
    const float* __restrict__ end1_w, const float* __restrict__ end1_b,
    const float* __restrict__ end2_w, const float* __restrict__ end2_b,
    const float* __restrict__ fc1_w,  const float* __restrict__ fc1_b,
    const float* __restrict__ fc2_w,  const float* __restrict__ fc2_b,
    const float* __restrict__ fc3_w,  const float* __restrict__ fc3_b,
    const float* __restrict__ fc4_w,  const float* __restrict__ fc4_b,
    float* __restrict__ out)
{
  __shared__ __align__(16) short bfw[2][7168];   // weight frags, double buffer
  __shared__ float bias2[2][128];
  __shared__ __align__(16) short xbuf[W0 * 32];
  __shared__ __align__(16) short pool[8624];     // emb stage (init) / rb+xm
  __shared__ int tok[W0];
  __shared__ float vecA[256], vecB[256];

  short* rb = pool;          // 76*32
  short* xm = pool + 2432;   // 76*32

  const int tid  = threadIdx.x;
  const int lane = tid & 63;
  const int wv   = tid >> 6;
  const int m    = lane & 31;
  const int kh   = lane >> 5;
  const int b    = blockIdx.x;

  // ---- tokens ----
  if (tid < W0) tok[tid] = tokens[b * TT + (TT - 1 - tid)];
  __syncthreads();

  // ---- stage emb rows (bf16, rows zero-padded to K=112) ----
  for (int cid = tid; cid < 77 * 14; cid += NT) {
    int u = cid / 14, s = cid % 14;
    const float* er = emb + tok[u] * 100 + s * 8;
    short8 v;
    if (s < 12) {
      #pragma unroll
      for (int j = 0; j < 8; j++) v[j] = f2bs(er[j]);
    } else if (s == 12) {
      #pragma unroll
      for (int j = 0; j < 4; j++) v[j] = f2bs(er[j]);
      #pragma unroll
      for (int j = 4; j < 8; j++) v[j] = 0;
    } else {
      #pragma unroll
      for (int j = 0; j < 8; j++) v[j] = 0;
    }
    *(short8*)&pool[u * 112 + s * 8] = v;
  }
  // stage layer-0 weight frags + biases directly (all threads)
  for (int cid = tid; cid < 896; cid += NT) {
    float pf[8];
    load_chunk(0, cid, pf, dil_w, filt_w, gate_w, res_w);
    short8 v;
    #pragma unroll
    for (int j = 0; j < 8; j++) v[j] = f2bs(pf[j]);
    *(short8*)&bfw[0][cid * 8] = v;
  }
  if (tid < 128) {
    const float* bsrc = (tid < 32) ? dil_b : (tid < 64) ? filt_b : (tid < 96) ? gate_b : res_b;
    bias2[0][tid] = bsrc[tid & 31];
  }
  __syncthreads();

  // ---- init conv (wave 0, MFMA over K=112) ----
  if (wv == 0) {
    short8 bi[7];
    #pragma unroll
    for (int s = 0; s < 7; s++) {
      const float* p = init_w + m * 100 + s * 16 + kh * 8;
      short8 v;
      if (s < 6) {
        #pragma unroll
        for (int j = 0; j < 8; j++) v[j] = f2bs(p[j]);
      } else if (kh == 0) {
        #pragma unroll
        for (int j = 0; j < 4; j++) v[j] = f2bs(p[j]);
        #pragma unroll
        for (int j = 4; j < 8; j++) v[j] = 0;
      } else {
        #pragma unroll
        for (int j = 0; j < 8; j++) v[j] = 0;
      }
      bi[s] = v;
    }
    const float binit = init_b[m];
    #pragma unroll
    for (int t = 0; t < 3; t++) {
      int R = t * 32;
      int u = R + m; if (u > 76) u = 76;
      float16 acc;
      #pragma unroll
      for (int r = 0; r < 16; r++) acc[r] = binit;
      #pragma unroll
      for (int s = 0; s < 7; s++) {
        short8 a = *(const short8*)&pool[u * 112 + s * 16 + kh * 8];
        acc = MFMA_B16(a, bi[s], acc);
      }
      #pragma unroll
      for (int r = 0; r < 16; r++) {
        int row = (r & 3) + 8 * (r >> 2) + 4 * kh;
        int uu = R + row;
        if (uu < W0) xbuf[uu * 32 + m] = f2bs(acc[r]);
      }
    }
  }
  __syncthreads();

  // ---- 16 layers, 2 barriers each; tiles parallel across waves ----
  int Win = W0;
  for (int i = 0; i < LL; i++) {
    const int d = 1 << (i & 3);
    const int Wout = Win - d - 1;
    const int T = (Wout + 32) >> 5;        // == tile count for both phases
    const short* bw = bfw[i & 1];
    const float* bs = bias2[i & 1];

    // prefetch layer i+1 chunks into regs (commit at layer bottom)
    float pf[4][8];
    float pbias = 0.f;
    const int nch = (tid < 128) ? 4 : 3;   // 896 = 3*256 + 128
    if (i + 1 < LL) {
      #pragma unroll
      for (int q = 0; q < 4; q++) {
        if (q < nch)
          load_chunk(i + 1, tid + q * NT, pf[q], dil_w, filt_w, gate_w, res_w);
      }
      if (tid < 128) {
        const float* bsrc = (tid < 32) ? dil_b : (tid < 64) ? filt_b : (tid < 96) ? gate_b : res_b;
        pbias = bsrc[(i + 1) * 32 + (tid & 31)];
      }
    }

    // phase1: residual[vr] = db + D0@x[vr+d] + D1@x[vr], rows [0,Wout]
    if (wv < T) {
      const int R = wv * 32;
      short8 B0[2], B1[2];
      #pragma unroll
      for (int h = 0; h < 2; h++) {
        B0[h] = *(const short8*)&bfw[i & 1][((0 * 2 + h) * 64 + lane) * 8];
        B1[h] = *(const short8*)&bfw[i & 1][((1 * 2 + h) * 64 + lane) * 8];
      }
      int vra = R + m + d; if (vra > Win - 1) vra = Win - 1;
      int vrz = R + m;     if (vrz > Win - 1) vrz = Win - 1;
      short8 aA[2], aZ[2];
      afrag2(xbuf, vra, kh, aA);
      afrag2(xbuf, vrz, kh, aZ);
      float16 acc;
      const float bc = bs[m];
      #pragma unroll
      for (int r = 0; r < 16; r++) acc[r] = bc;
      acc = MFMA_B16(aA[0], B0[0], acc);
      acc = MFMA_B16(aA[1], B0[1], acc);
      acc = MFMA_B16(aZ[0], B1[0], acc);
      acc = MFMA_B16(aZ[1], B1[1], acc);
      #pragma unroll
      for (int r = 0; r < 16; r++) {
        int row = (r & 3) + 8 * (r >> 2) + 4 * kh;
        int vr = R + row;
        if (vr <= Wout) rb[vr * 32 + m] = f2bs(acc[r]);
      }
    }
    __syncthreads();

    // phase2+3 (same wave & tile; wave-local xm handoff via lgkmcnt)
    if (wv < T) {
      const int R = wv * 32;
      short8 BW[5][2];
      #pragma unroll
      for (int mt = 0; mt < 5; mt++)
        #pragma unroll
        for (int h = 0; h < 2; h++)
          BW[mt][h] = *(const short8*)&bw[(((mt + 2) * 2 + h) * 64 + lane) * 8];
      int r1 = R + m + 1; if (r1 > Wout) r1 = Wout;
      int r0 = R + m;     if (r0 > Wout) r0 = Wout;
      short8 a1[2], a0[2];
      afrag2(rb, r1, kh, a1);
      afrag2(rb, r0, kh, a0);
      float16 accF, accG;
      const float bf = bs[32 + m], bg = bs[64 + m];
      #pragma unroll
      for (int r = 0; r < 16; r++) { accF[r] = bf; accG[r] = bg; }
      accF = MFMA_B16(a1[0], BW[0][0], accF);
      accF = MFMA_B16(a1[1], BW[0][1], accF);
      accF = MFMA_B16(a0[0], BW[1][0], accF);
      accF = MFMA_B16(a0[1], BW[1][1], accF);
      accG = MFMA_B16(a1[0], BW[2][0], accG);
      accG = MFMA_B16(a1[1], BW[2][1], accG);
      accG = MFMA_B16(a0[0], BW[3][0], accG);
      accG = MFMA_B16(a0[1], BW[3][1], accG);
      #pragma unroll
      for (int r = 0; r < 16; r++) {
        int row = (r & 3) + 8 * (r >> 2) + 4 * kh;
        int uf = R + row;
        if (uf < Wout)
          xm[uf * 32 + m] = f2bs(fast_tanh(accF[r]) * fast_sigmoid(accG[r]));
      }
      asm volatile("s_waitcnt lgkmcnt(0)" ::: "memory");

      // phase3: xnext = rbias + R@xmid + residual[row+1] (bf16 carry in C)
      int rx = R + m; if (rx > Wout - 1) rx = Wout - 1;
      short8 aX[2];
      afrag2(xm, rx, kh, aX);
      float16 accX;
      const float br = bs[96 + m];
      #pragma unroll
      for (int r = 0; r < 16; r++) {
        int row = (r & 3) + 8 * (r >> 2) + 4 * kh;
        int rr = R + row + 1; if (rr > Wout) rr = Wout;
        accX[r] = br + b2f(rb[rr * 32 + m]);
      }
      accX = MFMA_B16(aX[0], BW[4][0], accX);
      accX = MFMA_B16(aX[1], BW[4][1], accX);
      #pragma unroll
      for (int r = 0; r < 16; r++) {
        int row = (r & 3) + 8 * (r >> 2) + 4 * kh;
        int uf = R + row;
        if (uf < Wout) xbuf[uf * 32 + m] = f2bs(accX[r]);
      }
    }

    // commit layer i+1 frags (flip buffer; conflict-free b128 writes)
    if (i + 1 < LL) {
      short* dst = bfw[(i + 1) & 1];
      #pragma unroll
      for (int q = 0; q < 4; q++) {
        if (q < nch) {
          short8 v;
          #pragma unroll
          for (int j = 0; j < 8; j++) v[j] = f2bs(pf[q][j]);
          *(short8*)&dst[(tid + q * NT) * 8] = v;
        }
      }
      if (tid < 128) bias2[(i + 1) & 1][tid] = pbias;
    }
    __syncthreads();
    Win = Wout;
  }

  // ---- tail (f32 VALU, 4 waves): skip(l15) -> end1 -> end2 -> fc1..fc4 ----
  {
    float acc = skip_b[15 * 256 + tid];
    const float* wr = skip_w + (15 * 256 + tid) * 32;
    #pragma unroll
    for (int k = 0; k < 32; k += 4) {
      float4 w = *(const float4*)&wr[k];
      acc += (w.x * b2f(xm[k]) + w.y * b2f(xm[k+1])) + (w.z * b2f(xm[k+2]) + w.w * b2f(xm[k+3]));
    }
    vecA[tid] = fmaxf(acc, 0.f);
  }
  __syncthreads();
  {
    const float* wr = end1_w + tid * 256;
    float a4[4] = {0.f, 0.f, 0.f, 0.f};
    #pragma unroll 4
    for (int k = 0; k < 256; k += 16) {
      #pragma unroll
      for (int q = 0; q < 4; q++) {
        float4 w = *(const float4*)&wr[k + 4 * q];
        a4[q] += (w.x * vecA[k+4*q] + w.y * vecA[k+4*q+1]) + (w.z * vecA[k+4*q+2] + w.w * vecA[k+4*q+3]);
      }
    }
    vecB[tid] = fmaxf(end1_b[tid] + (a4[0] + a4[1]) + (a4[2] + a4[3]), 0.f);
  }
  __syncthreads();
  float h2;
  {
    const float* wr = end2_w + tid * 256;
    float a4[4] = {0.f, 0.f, 0.f, 0.f};
    #pragma unroll 4
    for (int k = 0; k < 256; k += 16) {
      #pragma unroll
      for (int q = 0; q < 4; q++) {
        float4 w = *(const float4*)&wr[k + 4 * q];
        a4[q] += (w.x * vecB[k+4*q] + w.y * vecB[k+4*q+1]) + (w.z * vecB[k+4*q+2] + w.w * vecB[k+4*q+3]);
      }
    }
    h2 = end2_b[tid] + (a4[0] + a4[1]) + (a4[2] + a4[3]);
  }
  __syncthreads();
  vecA[tid] = h2;
  __syncthreads();
  if (tid < 128) {
    const float* wr = fc1_w + tid * 256;
    float a4[4] = {0.f, 0.f, 0.f, 0.f};
    #pragma unroll 4
    for (int k = 0; k < 256; k += 16) {
      #pragma unroll
      for (int q = 0; q < 4; q++) {
        float4 w = *(const float4*)&wr[k + 4 * q];
        a4[q] += (w.x * vecA[k+4*q] + w.y * vecA[k+4*q+1]) + (w.z * vecA[k+4*q+2] + w.w * vecA[k+4*q+3]);
      }
    }
    vecB[tid] = fmaxf(fc1_b[tid] + (a4[0] + a4[1]) + (a4[2] + a4[3]), 0.f);
  }
  __syncthreads();
  if (tid < 128) {
    const float* wr = fc2_w + tid * 128;
    float a4[4] = {0.f, 0.f, 0.f, 0.f};
    #pragma unroll 2
    for (int k = 0; k < 128; k += 16) {
      #pragma unroll
      for (int q = 0; q < 4; q++) {
        float4 w = *(const float4*)&wr[k + 4 * q];
        a4[q] += (w.x * vecB[k+4*q] + w.y * vecB[k+4*q+1]) + (w.z * vecB[k+4*q+2] + w.w * vecB[k+4*q+3]);
      }
    }
    vecA[tid] = fmaxf(fc2_b[tid] + (a4[0] + a4[1]) + (a4[2] + a4[3]), 0.f);
  }
  __syncthreads();
  if (tid < 64) {
    const float* wr = fc3_w + tid * 128;
    float a4[4] = {0.f, 0.f, 0.f, 0.f};
    #pragma unroll 2
    for (int k = 0; k < 128; k += 16) {
      #pragma unroll
      for (int q = 0; q < 4; q++) {
        float4 w = *(const float4*)&wr[k + 4 * q];
        a4[q] += (w.x * vecA[k+4*q] + w.y * vecA[k+4*q+1]) + (w.z * vecA[k+4*q+2] + w.w * vecA[k+4*q+3]);
      }
    }
    vecB[tid] = fmaxf(fc3_b[tid] + (a4[0] + a4[1]) + (a4[2] + a4[3]), 0.f);
  }
  __syncthreads();
  {
    const float* wr = fc4_w + tid * 64;
    float a4[4] = {0.f, 0.f, 0.f, 0.f};
    #pragma unroll
    for (int k = 0; k < 64; k += 16) {
      #pragma unroll
      for (int q = 0; q < 4; q++) {
        float4 w = *(const float4*)&wr[k + 4 * q];
        a4[q] += (w.x * vecB[k+4*q] + w.y * vecB[k+4*q+1]) + (w.z * vecB[k+4*q+2] + w.w * vecB[k+4*q+3]);
      }
    }
    out[b * 256 + tid] = fc4_b[tid] + (a4[0] + a4[1]) + (a4[2] + a4[3]);
  }
}

extern "C" void kernel_launch(void* const* d_in, const int* in_sizes, int n_in,
                              void* d_out, int out_size, void* d_ws, size_t ws_size,
                              hipStream_t stream) {
  wavenet_kernel<<<BB, NT, 0, stream>>>(
      (const int*)d_in[0],    (const float*)d_in[1],  (const float*)d_in[2],  (const float*)d_in[3],
      (const float*)d_in[4],  (const float*)d_in[5],  (const float*)d_in[6],  (const float*)d_in[7],
      (const float*)d_in[8],  (const float*)d_in[9],  (const float*)d_in[10], (const float*)d_in[11],
      (const float*)d_in[12], (const float*)d_in[13], (const float*)d_in[14], (const float*)d_in[15],
      (const float*)d_in[16], (const float*)d_in[17], (const float*)d_in[18], (const float*)d_in[19],
      (const float*)d_in[20], (const float*)d_in[21], (const float*)d_in[22], (const float*)d_in[23],
      (const float*)d_in[24], (const float*)d_in[25], (float*)d_out);
}

// Round 11
// 211.228 us; speedup vs baseline: 1.2172x; 1.0044x over previous
//
#include <hip/hip_runtime.h>

// WaveNet inference on MFMA. Exploits: (1) only last timestep feeds the FC
// head, (2) skip overwritten each layer (only layer 15's matters),
// (3) receptive field at t=T-1 is 77 steps.
// Round 11 = R10 + single barrier per layer:
//  - each wave recomputes residual boundary row R+32 itself (VALU dot +
//    shfl_xor(32) partner add) -> phases 1-3 are wave-local, mid barrier gone
//  - layer-top barrier is raw s_barrier with lgkm-only drain (global
//    prefetch no longer drains at barriers, only at its commit consumer)

#define BB 16
#define TT 8192
#define LL 16
#define W0 77
#define NT 256

typedef __attribute__((ext_vector_type(8)))  short short8;
typedef __attribute__((ext_vector_type(16))) float float16;

#define MFMA_B16(a, b, c) __builtin_amdgcn_mfma_f32_32x32x16_bf16(a, b, c, 0, 0, 0)
#define LDS_FENCE() asm volatile("s_waitcnt lgkmcnt(0)" ::: "memory")
#define RAW_BARRIER() asm volatile("s_waitcnt lgkmcnt(0)\n\ts_barrier" ::: "memory")

__device__ __forceinline__ short f2bs(float f) {   // f32 -> bf16 bits, RNE
  union { float ff; unsigned u; } v; v.ff = f;
  unsigned u = v.u;
  return (short)((u + 0x7FFFu + ((u >> 16) & 1u)) >> 16);
}
__device__ __forceinline__ float b2f(short h) {
  union { unsigned u; float f; } v;
  v.u = ((unsigned)(unsigned short)h) << 16; return v.f;
}
__device__ __forceinline__ float fast_sigmoid(float x) {
  return 1.f / (1.f + __expf(-x));
}
__device__ __forceinline__ float fast_tanh(float x) {
  return 2.f / (1.f + __expf(-2.f * x)) - 1.f;
}

// A-fragment halves from [row][32] bf16 LDS: A[m][k], k-local=(lane>>5)*8+j.
__device__ __forceinline__ void afrag2(const short* src, int row, int kh, short8* out) {
  out[0] = *(const short8*)&src[row * 32 + 8 * kh];
  out[1] = *(const short8*)&src[row * 32 + 16 + 8 * kh];
}

// chunk cid in [0,896): mat=cid>>7, h=(cid>>6)&1, ln=cid&63 -> n=ln&31,k2=ln>>5
// value j: W[16h+8k2+j][n] of matrix mat; dst offset = cid*8 shorts (b128).
__device__ __forceinline__ void load_chunk(
    int li, int cid, float* pf,
    const float* dil_w, const float* filt_w, const float* gate_w, const float* res_w)
{
  int mat = cid >> 7;
  int h = (cid >> 6) & 1, ln = cid & 63;
  int n = ln & 31, k2 = ln >> 5;
  int base = (li * 32 + n) * 32 + 16 * h + 8 * k2;
  if (mat == 6) {
    const float* p = res_w + base;
    #pragma unroll
    for (int j = 0; j < 8; j++) pf[j] = p[j];
  } else {
    const float* w = (mat < 2) ? dil_w : (mat < 4) ? filt_w : gate_w;
    const float* p = w + base * 2 + (mat & 1);
    #pragma unroll
    for (int j = 0; j < 8; j++) pf[j] = p[2 * j];
  }
}

__global__ __launch_bounds__(NT, 1) void wavenet_kernel(
    const int* __restrict__ tokens,
    const float* __restrict__ emb,
    const float* __restrict__ init_w, const float* __restrict__ init_b,
    const float* __restrict__ dil_w,  const float* __restrict__ dil_b,
    const float* __restrict__ filt_w, const float* __restrict__ filt_b,
    const float* __restrict__ gate_w, const float* __restrict__ gate_b,
    const float* __restrict__ res_w,  const float* __restrict__ res_b,
    const float* __restrict__ skip_w, const float* __restrict__ skip_b,
    const float* __restrict__ end1_w, const float* __restrict__ end1_b,
    const float* __restrict__ end2_w, const float* __restrict__ end2_b,
    const float* __restrict__ fc1_w,  const float* __restrict__ fc1_b,
    const float* __restrict__ fc2_w,  const float* __restrict__ fc2_b,
    const float* __restrict__ fc3_w,  const float* __restrict__ fc3_b,
    const float* __restrict__ fc4_w,  const float* __restrict__ fc4_b,
    float* __restrict__ out)
{
  __shared__ __align__(16) short bfw[2][7168];   // weight frags, double buffer
  __shared__ float bias2[2][128];
  __shared__ __align__(16) short xbuf[W0 * 32];
  __shared__ __align__(16) short pool[8624];     // emb stage (init) / rb+xm
  __shared__ int tok[W0];
  __shared__ float vecA[256], vecB[256];

  short* rb = pool;          // 77*32 (row 76+boundary fits: rows 0..76)
  short* xm = pool + 2464;   // 76*32

  const int tid  = threadIdx.x;
  const int lane = tid & 63;
  const int wv   = tid >> 6;
  const int m    = lane & 31;
  const int kh   = lane >> 5;
  const int b    = blockIdx.x;

  // ---- tokens ----
  if (tid < W0) tok[tid] = tokens[b * TT + (TT - 1 - tid)];
  __syncthreads();

  // ---- stage emb rows (bf16, rows zero-padded to K=112) ----
  for (int cid = tid; cid < 77 * 14; cid += NT) {
    int u = cid / 14, s = cid % 14;
    const float* er = emb + tok[u] * 100 + s * 8;
    short8 v;
    if (s < 12) {
      #pragma unroll
      for (int j = 0; j < 8; j++) v[j] = f2bs(er[j]);
    } else if (s == 12) {
      #pragma unroll
      for (int j = 0; j < 4; j++) v[j] = f2bs(er[j]);
      #pragma unroll
      for (int j = 4; j < 8; j++) v[j] = 0;
    } else {
      #pragma unroll
      for (int j = 0; j < 8; j++) v[j] = 0;
    }
    *(short8*)&pool[u * 112 + s * 8] = v;
  }
  // stage layer-0 weight frags + biases (all threads)
  for (int cid = tid; cid < 896; cid += NT) {
    float pf[8];
    load_chunk(0, cid, pf, dil_w, filt_w, gate_w, res_w);
    short8 v;
    #pragma unroll
    for (int j = 0; j < 8; j++) v[j] = f2bs(pf[j]);
    *(short8*)&bfw[0][cid * 8] = v;
  }
  if (tid < 128) {
    const float* bsrc = (tid < 32) ? dil_b : (tid < 64) ? filt_b : (tid < 96) ? gate_b : res_b;
    bias2[0][tid] = bsrc[tid & 31];
  }
  __syncthreads();

  // ---- init conv (wave 0, MFMA over K=112) ----
  if (wv == 0) {
    short8 bi[7];
    #pragma unroll
    for (int s = 0; s < 7; s++) {
      const float* p = init_w + m * 100 + s * 16 + kh * 8;
      short8 v;
      if (s < 6) {
        #pragma unroll
        for (int j = 0; j < 8; j++) v[j] = f2bs(p[j]);
      } else if (kh == 0) {
        #pragma unroll
        for (int j = 0; j < 4; j++) v[j] = f2bs(p[j]);
        #pragma unroll
        for (int j = 4; j < 8; j++) v[j] = 0;
      } else {
        #pragma unroll
        for (int j = 0; j < 8; j++) v[j] = 0;
      }
      bi[s] = v;
    }
    const float binit = init_b[m];
    #pragma unroll
    for (int t = 0; t < 3; t++) {
      int R = t * 32;
      int u = R + m; if (u > 76) u = 76;
      float16 acc;
      #pragma unroll
      for (int r = 0; r < 16; r++) acc[r] = binit;
      #pragma unroll
      for (int s = 0; s < 7; s++) {
        short8 a = *(const short8*)&pool[u * 112 + s * 16 + kh * 8];
        acc = MFMA_B16(a, bi[s], acc);
      }
      #pragma unroll
      for (int r = 0; r < 16; r++) {
        int row = (r & 3) + 8 * (r >> 2) + 4 * kh;
        int uu = R + row;
        if (uu < W0) xbuf[uu * 32 + m] = f2bs(acc[r]);
      }
    }
  }

  // ---- 16 layers, ONE raw barrier each; phases wave-local ----
  int Win = W0;
  for (int i = 0; i < LL; i++) {
    RAW_BARRIER();   // xbuf (prev phase3) + commit (weights) visible
    const int d = 1 << (i & 3);
    const int Wout = Win - d - 1;
    const int T = (Wout + 32) >> 5;
    const short* bw = bfw[i & 1];
    const float* bs = bias2[i & 1];

    // prefetch layer i+1 chunks into regs (commit at layer bottom)
    float pf[4][8];
    float pbias = 0.f;
    const int nch = (tid < 128) ? 4 : 3;   // 896 = 3*256 + 128
    if (i + 1 < LL) {
      #pragma unroll
      for (int q = 0; q < 4; q++) {
        if (q < nch)
          load_chunk(i + 1, tid + q * NT, pf[q], dil_w, filt_w, gate_w, res_w);
      }
      if (tid < 128) {
        const float* bsrc = (tid < 32) ? dil_b : (tid < 64) ? filt_b : (tid < 96) ? gate_b : res_b;
        pbias = bsrc[(i + 1) * 32 + (tid & 31)];
      }
    }

    if (wv < T) {
      const int R = wv * 32;
      // phase1 weights
      short8 B0[2], B1[2];
      #pragma unroll
      for (int h = 0; h < 2; h++) {
        B0[h] = *(const short8*)&bw[((0 * 2 + h) * 64 + lane) * 8];
        B1[h] = *(const short8*)&bw[((1 * 2 + h) * 64 + lane) * 8];
      }
      // phase1 tile: residual[vr] = db + D0@x[vr+d] + D1@x[vr]
      int vra = R + m + d; if (vra > Win - 1) vra = Win - 1;
      int vrz = R + m;     if (vrz > Win - 1) vrz = Win - 1;
      short8 aA[2], aZ[2];
      afrag2(xbuf, vra, kh, aA);
      afrag2(xbuf, vrz, kh, aZ);
      float16 acc;
      const float bc = bs[m];
      #pragma unroll
      for (int r = 0; r < 16; r++) acc[r] = bc;
      acc = MFMA_B16(aA[0], B0[0], acc);
      acc = MFMA_B16(aA[1], B0[1], acc);
      acc = MFMA_B16(aZ[0], B1[0], acc);
      acc = MFMA_B16(aZ[1], B1[1], acc);
      #pragma unroll
      for (int r = 0; r < 16; r++) {
        int row = (r & 3) + 8 * (r >> 2) + 4 * kh;
        int vr = R + row;
        if (vr <= Wout) rb[vr * 32 + m] = f2bs(acc[r]);
      }

      // boundary row Bv = R+32 (tile t+1's first row), self-computed:
      // lane (m,kh) holds D0/D1 column-m entries for k in its frag slices.
      const int Bv = R + 32;
      if (Bv <= Wout) {
        // Bv <= Wout = Win-d-1  =>  Bv+d <= Win-1 (no clamp needed)
        short8 xa0 = *(const short8*)&xbuf[(Bv + d) * 32 + 8 * kh];
        short8 xa1 = *(const short8*)&xbuf[(Bv + d) * 32 + 16 + 8 * kh];
        short8 xz0 = *(const short8*)&xbuf[Bv * 32 + 8 * kh];
        short8 xz1 = *(const short8*)&xbuf[Bv * 32 + 16 + 8 * kh];
        float p = 0.f;
        #pragma unroll
        for (int j = 0; j < 8; j++) {
          p += b2f(B0[0][j]) * b2f(xa0[j]) + b2f(B0[1][j]) * b2f(xa1[j]);
          p += b2f(B1[0][j]) * b2f(xz0[j]) + b2f(B1[1][j]) * b2f(xz1[j]);
        }
        p += __shfl_xor(p, 32, 64);        // add partner k-half
        if (kh == 0) rb[Bv * 32 + m] = f2bs(p + bc);
      }
      LDS_FENCE();   // rb writes visible to this wave's own reads

      // phase2: f/g from rb rows [R..R+32] (all wave-local now)
      short8 BW[5][2];
      #pragma unroll
      for (int mt = 0; mt < 5; mt++)
        #pragma unroll
        for (int h = 0; h < 2; h++)
          BW[mt][h] = *(const short8*)&bw[(((mt + 2) * 2 + h) * 64 + lane) * 8];
      int r1 = R + m + 1; if (r1 > Wout) r1 = Wout;
      int r0 = R + m;     if (r0 > Wout) r0 = Wout;
      short8 a1[2], a0[2];
      afrag2(rb, r1, kh, a1);
      afrag2(rb, r0, kh, a0);
      float16 accF, accG;
      const float bf = bs[32 + m], bg = bs[64 + m];
      #pragma unroll
      for (int r = 0; r < 16; r++) { accF[r] = bf; accG[r] = bg; }
      accF = MFMA_B16(a1[0], BW[0][0], accF);
      accF = MFMA_B16(a1[1], BW[0][1], accF);
      accF = MFMA_B16(a0[0], BW[1][0], accF);
      accF = MFMA_B16(a0[1], BW[1][1], accF);
      accG = MFMA_B16(a1[0], BW[2][0], accG);
      accG = MFMA_B16(a1[1], BW[2][1], accG);
      accG = MFMA_B16(a0[0], BW[3][0], accG);
      accG = MFMA_B16(a0[1], BW[3][1], accG);
      #pragma unroll
      for (int r = 0; r < 16; r++) {
        int row = (r & 3) + 8 * (r >> 2) + 4 * kh;
        int uf = R + row;
        if (uf < Wout)
          xm[uf * 32 + m] = f2bs(fast_tanh(accF[r]) * fast_sigmoid(accG[r]));
      }
      LDS_FENCE();

      // phase3: xnext = rbias + R@xmid + residual[row+1] (bf16 carry in C)
      int rx = R + m; if (rx > Wout - 1) rx = Wout - 1;
      short8 aX[2];
      afrag2(xm, rx, kh, aX);
      float16 accX;
      const float br = bs[96 + m];
      #pragma unroll
      for (int r = 0; r < 16; r++) {
        int row = (r & 3) + 8 * (r >> 2) + 4 * kh;
        int rr = R + row + 1; if (rr > Wout) rr = Wout;
        accX[r] = br + b2f(rb[rr * 32 + m]);
      }
      accX = MFMA_B16(aX[0], BW[4][0], accX);
      accX = MFMA_B16(aX[1], BW[4][1], accX);
      #pragma unroll
      for (int r = 0; r < 16; r++) {
        int row = (r & 3) + 8 * (r >> 2) + 4 * kh;
        int uf = R + row;
        if (uf < Wout) xbuf[uf * 32 + m] = f2bs(accX[r]);
      }
    }

    // commit layer i+1 frags (flip buffer; conflict-free b128 writes)
    if (i + 1 < LL) {
      short* dst = bfw[(i + 1) & 1];
      #pragma unroll
      for (int q = 0; q < 4; q++) {
        if (q < nch) {
          short8 v;
          #pragma unroll
          for (int j = 0; j < 8; j++) v[j] = f2bs(pf[q][j]);
          *(short8*)&dst[(tid + q * NT) * 8] = v;
        }
      }
      if (tid < 128) bias2[(i + 1) & 1][tid] = pbias;
    }
    Win = Wout;
  }
  __syncthreads();

  // ---- tail (f32 VALU, 4 waves): skip(l15) -> end1 -> end2 -> fc1..fc4 ----
  {
    float acc = skip_b[15 * 256 + tid];
    const float* wr = skip_w + (15 * 256 + tid) * 32;
    #pragma unroll
    for (int k = 0; k < 32; k += 4) {
      float4 w = *(const float4*)&wr[k];
      acc += (w.x * b2f(xm[k]) + w.y * b2f(xm[k+1])) + (w.z * b2f(xm[k+2]) + w.w * b2f(xm[k+3]));
    }
    vecA[tid] = fmaxf(acc, 0.f);
  }
  __syncthreads();
  {
    const float* wr = end1_w + tid * 256;
    float a4[4] = {0.f, 0.f, 0.f, 0.f};
    #pragma unroll 4
    for (int k = 0; k < 256; k += 16) {
      #pragma unroll
      for (int q = 0; q < 4; q++) {
        float4 w = *(const float4*)&wr[k + 4 * q];
        a4[q] += (w.x * vecA[k+4*q] + w.y * vecA[k+4*q+1]) + (w.z * vecA[k+4*q+2] + w.w * vecA[k+4*q+3]);
      }
    }
    vecB[tid] = fmaxf(end1_b[tid] + (a4[0] + a4[1]) + (a4[2] + a4[3]), 0.f);
  }
  __syncthreads();
  float h2;
  {
    const float* wr = end2_w + tid * 256;
    float a4[4] = {0.f, 0.f, 0.f, 0.f};
    #pragma unroll 4
    for (int k = 0; k < 256; k += 16) {
      #pragma unroll
      for (int q = 0; q < 4; q++) {
        float4 w = *(const float4*)&wr[k + 4 * q];
        a4[q] += (w.x * vecB[k+4*q] + w.y * vecB[k+4*q+1]) + (w.z * vecB[k+4*q+2] + w.w * vecB[k+4*q+3]);
      }
    }
    h2 = end2_b[tid] + (a4[0] + a4[1]) + (a4[2] + a4[3]);
  }
  __syncthreads();
  vecA[tid] = h2;
  __syncthreads();
  if (tid < 128) {
    const float* wr = fc1_w + tid * 256;
    float a4[4] = {0.f, 0.f, 0.f, 0.f};
    #pragma unroll 4
    for (int k = 0; k < 256; k += 16) {
      #pragma unroll
      for (int q = 0; q < 4; q++) {
        float4 w = *(const float4*)&wr[k + 4 * q];
        a4[q] += (w.x * vecA[k+4*q] + w.y * vecA[k+4*q+1]) + (w.z * vecA[k+4*q+2] + w.w * vecA[k+4*q+3]);
      }
    }
    vecB[tid] = fmaxf(fc1_b[tid] + (a4[0] + a4[1]) + (a4[2] + a4[3]), 0.f);
  }
  __syncthreads();
  if (tid < 128) {
    const float* wr = fc2_w + tid * 128;
    float a4[4] = {0.f, 0.f, 0.f, 0.f};
    #pragma unroll 2
    for (int k = 0; k < 128; k += 16) {
      #pragma unroll
      for (int q = 0; q < 4; q++) {
        float4 w = *(const float4*)&wr[k + 4 * q];
        a4[q] += (w.x * vecB[k+4*q] + w.y * vecB[k+4*q+1]) + (w.z * vecB[k+4*q+2] + w.w * vecB[k+4*q+3]);
      }
    }
    vecA[tid] = fmaxf(fc2_b[tid] + (a4[0] + a4[1]) + (a4[2] + a4[3]), 0.f);
  }
  __syncthreads();
  if (tid < 64) {
    const float* wr = fc3_w + tid * 128;
    float a4[4] = {0.f, 0.f, 0.f, 0.f};
    #pragma unroll 2
    for (int k = 0; k < 128; k += 16) {
      #pragma unroll
      for (int q = 0; q < 4; q++) {
        float4 w = *(const float4*)&wr[k + 4 * q];
        a4[q] += (w.x * vecA[k+4*q] + w.y * vecA[k+4*q+1]) + (w.z * vecA[k+4*q+2] + w.w * vecA[k+4*q+3]);
      }
    }
    vecB[tid] = fmaxf(fc3_b[tid] + (a4[0] + a4[1]) + (a4[2] + a4[3]), 0.f);
  }
  __syncthreads();
  {
    const float* wr = fc4_w + tid * 64;
    float a4[4] = {0.f, 0.f, 0.f, 0.f};
    #pragma unroll
    for (int k = 0; k < 64; k += 16) {
      #pragma unroll
      for (int q = 0; q < 4; q++) {
        float4 w = *(const float4*)&wr[k + 4 * q];
        a4[q] += (w.x * vecB[k+4*q] + w.y * vecB[k+4*q+1]) + (w.z * vecB[k+4*q+2] + w.w * vecB[k+4*q+3]);
      }
    }
    out[b * 256 + tid] = fc4_b[tid] + (a4[0] + a4[1]) + (a4[2] + a4[3]);
  }
}

extern "C" void kernel_launch(void* const* d_in, const int* in_sizes, int n_in,
                              void* d_out, int out_size, void* d_ws, size_t ws_size,
                              hipStream_t stream) {
  wavenet_kernel<<<BB, NT, 0, stream>>>(
      (const int*)d_in[0],    (const float*)d_in[1],  (const float*)d_in[2],  (const float*)d_in[3],
      (const float*)d_in[4],  (const float*)d_in[5],  (const float*)d_in[6],  (const float*)d_in[7],
      (const float*)d_in[8],  (const float*)d_in[9],  (const float*)d_in[10], (const float*)d_in[11],
      (const float*)d_in[12], (const float*)d_in[13], (const float*)d_in[14], (const float*)d_in[15],
      (const float*)d_in[16], (const float*)d_in[17], (const float*)d_in[18], (const float*)d_in[19],
      (const float*)d_in[20], (const float*)d_in[21], (const float*)d_in[22], (const float*)d_in[23],
      (const float*)d_in[24], (const float*)d_in[25], (float*)d_out);
}